// Round 3
// baseline (252.279 us; speedup 1.0000x reference)
//
#include <hip/hip_runtime.h>

// MV_GCN on MI355X — round 5: occupancy attack on the fused GCN kernel.
// Round-1 fused kernel was latency-bound (VALUBusy 38%, Occ 33%) with LDS
// 54.3 KB capping residency at 2 blocks/CU. Split each (g,v) across TWO
// blocks of 58 output rows: LDS 58x116 f32 + deg + dinv = 27.8 KB ->
// 4 blocks/CU = 32 waves = 100% occupancy. Grid 1024 = 4 x 256 CUs exact.
// Degree is built with a second LDS atomic into deg[116] (both half-blocks
// scan all edges of their (g,v); edges are L3-resident, re-read is cheap).
// bid swizzle: both halves of a (g,v) land on the same XCD (L2 reuse).

#define NB 256
#define NODES 116
#define FEAT 115
#define LENN 6670
#define SEG2 13456
#define HID 128
#define HC 512
#define HROWS 58   // output rows per block (116 / 2)
#define ASTR 116   // row stride (464 B = 29*16, float4-aligned rows)

__global__ __launch_bounds__(512, 8) void k_fused(
    const float* __restrict__ x, const int* __restrict__ ei,
    const float* __restrict__ ew,
    const float* __restrict__ W1, const float* __restrict__ b1,
    const float* __restrict__ W2, const float* __restrict__ b2,
    float* __restrict__ featws)
{
  __shared__ __align__(16) float sA[HROWS * ASTR];   // A_hat half, then M half
  __shared__ float deg[NODES];
  __shared__ float dinv[NODES];
  const int rawbid = blockIdx.x;
  // swizzle: rawbid = (b<<4)|(h<<3)|a  ->  gv = a + 8b, half = h.
  // halves of one (g,v) sit 8 apart in dispatch order -> same XCD (mod 8).
  const int a_ = rawbid & 7, h = (rawbid >> 3) & 1, b_ = rawbid >> 4;
  const int gv = a_ + 8 * b_;          // [0, 512)
  const int g = gv >> 1, v = gv & 1;
  const int rbase = h * HROWS;         // first global dst row of this block
  const int tid = threadIdx.x;

  // ---- phase 0: zero sA (58*116 = 6728 f32 = 1682 float4) and deg
  const float4 z4 = make_float4(0.f, 0.f, 0.f, 0.f);
  for (int i = tid; i < (HROWS * ASTR) / 4; i += 512) ((float4*)sA)[i] = z4;
  if (tid < NODES) deg[tid] = 0.f;
  __syncthreads();

  // ---- phase 1: one edge pass: deg[d] += w (all rows), A[d][s] += w (ours)
  const int eoff = g * SEG2 + v * LENN;
  const int nbase = g * 232 + v * 116;
  const int* __restrict__ srcp = ei + eoff;
  const int* __restrict__ dstp = ei + (size_t)NB * SEG2 + eoff;
  const float* __restrict__ wp = ew + eoff;
#pragma unroll 4
  for (int q = tid; q < (LENN / 2); q += 512) {
    int2 s2 = ((const int2*)srcp)[q];
    int2 d2 = ((const int2*)dstp)[q];
    float2 w2 = ((const float2*)wp)[q];
    const int dl0 = d2.x - nbase, dl1 = d2.y - nbase;     // 0..115
    atomicAdd(&deg[dl0], w2.x);
    atomicAdd(&deg[dl1], w2.y);
    const int r0 = dl0 - rbase, r1 = dl1 - rbase;
    if ((unsigned)r0 < HROWS) atomicAdd(&sA[r0 * ASTR + (s2.x - nbase)], w2.x);
    if ((unsigned)r1 < HROWS) atomicAdd(&sA[r1 * ASTR + (s2.y - nbase)], w2.y);
  }
  __syncthreads();

  // ---- phase 2: dinv for ALL nodes
  if (tid < NODES) dinv[tid] = rsqrtf(deg[tid] + 1.0f);   // deg + self-loop
  __syncthreads();

  // ---- phase 3: normalize our rows; fold self-loop dinv^2 into diagonal
  for (int idx = tid; idx < HROWS * ASTR; idx += 512) {
    int dl = idx / ASTR;
    int s = idx - dl * ASTR;
    int dg = rbase + dl;
    float di = dinv[dg];
    float val = sA[idx] * (di * dinv[s]);
    if (dg == s) val += di * di;
    sA[idx] = val;
  }
  __syncthreads();

  // ---- phase 4: M = A_hat(LDS f4 bcast) @ X(global per-lane, dbuf)
  const int cg64 = tid & 63, rg = tid >> 6;
  const int c0 = cg64 * 2;
  const float* __restrict__ Xg = x + (size_t)nbase * FEAT;
  const bool p0 = (c0 < FEAT);
  const bool p1 = (c0 + 1 < FEAT);

  float2 macc[8];
#pragma unroll
  for (int i = 0; i < 8; ++i) macc[i] = make_float2(0.f, 0.f);

  float2 xc[4], xn[4];
#pragma unroll
  for (int j = 0; j < 4; ++j) {
    xn[j].x = p0 ? Xg[(size_t)j * FEAT + c0] : 0.f;
    xn[j].y = p1 ? Xg[(size_t)j * FEAT + c0 + 1] : 0.f;
  }

  for (int sc = 0; sc < 29; ++sc) {          // K = 116 nodes, 29*4 exact
#pragma unroll
    for (int j = 0; j < 4; ++j) xc[j] = xn[j];
    if (sc < 28) {
      const int sn = 4 * (sc + 1);
#pragma unroll
      for (int j = 0; j < 4; ++j) {
        xn[j].x = p0 ? Xg[(size_t)(sn + j) * FEAT + c0] : 0.f;
        xn[j].y = p1 ? Xg[(size_t)(sn + j) * FEAT + c0 + 1] : 0.f;
      }
    }
    const int s0 = 4 * sc;
#pragma unroll
    for (int i = 0; i < 8; ++i) {
      int r = rg + 8 * i;
      r = (r < HROWS) ? r : (HROWS - 1);
      float4 aq = *(const float4*)&sA[r * ASTR + s0];  // wave-uniform bcast
      macc[i].x = fmaf(aq.x, xc[0].x, macc[i].x);
      macc[i].x = fmaf(aq.y, xc[1].x, macc[i].x);
      macc[i].x = fmaf(aq.z, xc[2].x, macc[i].x);
      macc[i].x = fmaf(aq.w, xc[3].x, macc[i].x);
      macc[i].y = fmaf(aq.x, xc[0].y, macc[i].y);
      macc[i].y = fmaf(aq.y, xc[1].y, macc[i].y);
      macc[i].y = fmaf(aq.z, xc[2].y, macc[i].y);
      macc[i].y = fmaf(aq.w, xc[3].y, macc[i].y);
    }
  }
  __syncthreads();   // everyone done reading A_hat

  // ---- phase 5: M overwrites sA (cols 0..115; col 115 == 0 from X pad)
  if (c0 < ASTR) {
#pragma unroll
    for (int i = 0; i < 8; ++i) {
      int r = rg + 8 * i;
      r = (r < HROWS) ? r : (HROWS - 1);   // clamped slots: same value, benign
      *(float2*)&sA[r * ASTR + c0] = macc[i];
    }
  }
  __syncthreads();

  // ---- phase 6: out = M(LDS f4 bcast) @ W(global per-lane, dbuf) + b
  const float* __restrict__ W = v ? W2 : W1;
  const float* __restrict__ bv = v ? b2 : b1;
  const float* __restrict__ Wc = W + c0;

  float2 bb = *(const float2*)(bv + c0);
  float2 acc[8];
#pragma unroll
  for (int i = 0; i < 8; ++i) acc[i] = bb;

  float2 wc[4], wn[4];
#pragma unroll
  for (int j = 0; j < 4; ++j) wn[j] = *(const float2*)(Wc + (size_t)j * HID);

  for (int kc = 0; kc < 29; ++kc) {          // k = 0..115 (M col 115 = 0)
#pragma unroll
    for (int j = 0; j < 4; ++j) wc[j] = wn[j];
    if (kc < 27) {
      const int kn = 4 * (kc + 1);
#pragma unroll
      for (int j = 0; j < 4; ++j)
        wn[j] = *(const float2*)(Wc + (size_t)(kn + j) * HID);
    } else if (kc == 27) {                   // tail rows 112..114 + zero row
#pragma unroll
      for (int j = 0; j < 3; ++j)
        wn[j] = *(const float2*)(Wc + (size_t)(112 + j) * HID);
      wn[3] = make_float2(0.f, 0.f);
    }
    const int k0 = 4 * kc;
#pragma unroll
    for (int i = 0; i < 8; ++i) {
      int r = rg + 8 * i;
      r = (r < HROWS) ? r : (HROWS - 1);
      float4 aq = *(const float4*)&sA[r * ASTR + k0];  // wave-uniform bcast
      acc[i].x = fmaf(aq.x, wc[0].x, acc[i].x);
      acc[i].x = fmaf(aq.y, wc[1].x, acc[i].x);
      acc[i].x = fmaf(aq.z, wc[2].x, acc[i].x);
      acc[i].x = fmaf(aq.w, wc[3].x, acc[i].x);
      acc[i].y = fmaf(aq.x, wc[0].y, acc[i].y);
      acc[i].y = fmaf(aq.y, wc[1].y, acc[i].y);
      acc[i].y = fmaf(aq.z, wc[2].y, acc[i].y);
      acc[i].y = fmaf(aq.w, wc[3].y, acc[i].y);
    }
  }

  // ---- phase 7: channel max across the wave (2 channels/lane)
#pragma unroll
  for (int i = 0; i < 8; ++i) {
    int r = rg + 8 * i;
    r = (r < HROWS) ? r : (HROWS - 1);
    float m = fmaxf(acc[i].x, acc[i].y);
#pragma unroll
    for (int off = 32; off >= 1; off >>= 1)
      m = fmaxf(m, __shfl_xor(m, off, 64));
    if (cg64 == 0)
      featws[g * 232 + 2 * (rbase + r) + v] = m;  // stack([x1,x2],1).reshape
  }
}

// ---------------- K2: MLP  relu(feat@W6+b6)@W7+b7 ----------------
__global__ __launch_bounds__(512) void k_mlp(
    const float* __restrict__ featws, const float* __restrict__ W6,
    const float* __restrict__ b6, const float* __restrict__ W7,
    const float* __restrict__ b7, float* __restrict__ out)
{
  __shared__ float sf[232];
  __shared__ float red[8];
  const int g = blockIdx.x, tid = threadIdx.x;
  if (tid < 232) sf[tid] = featws[g * 232 + tid];
  __syncthreads();

  float a = b6[tid];
  const float* __restrict__ w6p = W6 + tid;
#pragma unroll 8
  for (int k = 0; k < 232; ++k)
    a = fmaf(sf[k], w6p[(size_t)k * HC], a);
  a = fmaxf(a, 0.f);
  float p = a * W7[tid];
#pragma unroll
  for (int off = 32; off >= 1; off >>= 1) p += __shfl_xor(p, off, 64);
  if ((tid & 63) == 0) red[tid >> 6] = p;
  __syncthreads();
  if (tid == 0) {
    float t = b7[0];
#pragma unroll
    for (int i = 0; i < 8; ++i) t += red[i];
    out[g] = t;
  }
}

extern "C" void kernel_launch(void* const* d_in, const int* in_sizes, int n_in,
                              void* d_out, int out_size, void* d_ws, size_t ws_size,
                              hipStream_t stream)
{
  const float* x  = (const float*)d_in[0];
  const int*   ei = (const int*)d_in[1];
  const float* ew = (const float*)d_in[2];
  // d_in[3] = batch (unused by reference)
  const float* W1 = (const float*)d_in[4];
  const float* b1 = (const float*)d_in[5];
  const float* W2 = (const float*)d_in[6];
  const float* b2 = (const float*)d_in[7];
  const float* W6 = (const float*)d_in[8];
  const float* b6 = (const float*)d_in[9];
  const float* W7 = (const float*)d_in[10];
  const float* b7 = (const float*)d_in[11];

  float* featws = (float*)d_ws;                 // 256*232 f32 = 237 KB
  float* out    = (float*)d_out;

  hipLaunchKernelGGL(k_fused, dim3(4 * NB), dim3(512), 0, stream,
                     x, ei, ew, W1, b1, W2, b2, featws);
  hipLaunchKernelGGL(k_mlp,   dim3(NB),     dim3(512), 0, stream,
                     featws, W6, b6, W7, b7, out);
}